// Round 1
// 262.707 us; speedup vs baseline: 1.0496x; 1.0496x over previous
//
#include <hip/hip_runtime.h>
#include <hip/hip_bf16.h>

#define HDIM 2048
#define NHEADS 32
#define HEADD 64
#define NBATCH 2
#define SEQLEN 2048
#define MTOT (NBATCH * SEQLEN)
#define NQT (SEQLEN / 128)   // 16 q-tiles of 128 rows
#define LDQKV 6144           // fused QKV row stride

typedef __bf16 bf16;
typedef __bf16 bf16x8 __attribute__((ext_vector_type(8)));
typedef float f32x4 __attribute__((ext_vector_type(4)));
typedef float f32x8 __attribute__((ext_vector_type(8)));
typedef float f32x16 __attribute__((ext_vector_type(16)));

// global -> LDS async copy, 16B per lane; LDS dest is wave-uniform base + lane*16
__device__ __forceinline__ void gload_lds16(const bf16* g, bf16* l) {
  __builtin_amdgcn_global_load_lds(
      (const __attribute__((address_space(1))) void*)g,
      (__attribute__((address_space(3))) void*)l, 16, 0, 0);
}

__device__ __forceinline__ unsigned cvtpk_bf16(float lo, float hi) {
  unsigned r;
  asm("v_cvt_pk_bf16_f32 %0, %1, %2" : "=v"(r) : "v"(lo), "v"(hi));
  return r;
}

__device__ __forceinline__ float max3f(float a, float b, float c) {
  float r;
  asm("v_max3_f32 %0, %1, %2, %3" : "=v"(r) : "v"(a), "v"(b), "v"(c));
  return r;
}

__global__ void __launch_bounds__(256) cvt_f32_to_bf16(
    const float* __restrict__ src, bf16* __restrict__ dst, int n) {
  int i = (blockIdx.x * 256 + threadIdx.x) * 8;
  if (i >= n) return;
  f32x8 a = *(const f32x8*)(src + i);
  bf16x8 o;
#pragma unroll
  for (int j = 0; j < 8; ++j) o[j] = (bf16)a[j];
  *(bf16x8*)(dst + i) = o;
}

// 4 weight matrices in one dispatch (blockIdx.y selects)
__global__ void __launch_bounds__(256) cvt4_f32_to_bf16(
    const float* __restrict__ s0, const float* __restrict__ s1,
    const float* __restrict__ s2, const float* __restrict__ s3,
    bf16* __restrict__ d0, bf16* __restrict__ d1,
    bf16* __restrict__ d2, bf16* __restrict__ d3) {
  const float* src; bf16* dst;
  switch (blockIdx.y) {
    case 0: src = s0; dst = d0; break;
    case 1: src = s1; dst = d1; break;
    case 2: src = s2; dst = d2; break;
    default: src = s3; dst = d3; break;
  }
  int i = (blockIdx.x * 256 + threadIdx.x) * 8;
  f32x8 a = *(const f32x8*)(src + i);
  bf16x8 o;
#pragma unroll
  for (int j = 0; j < 8; ++j) o[j] = (bf16)a[j];
  *(bf16x8*)(dst + i) = o;
}

// pack bq|bk|bv -> biasqkv[6144]
__global__ void __launch_bounds__(256) pack_bias(
    const float* __restrict__ bq, const float* __restrict__ bk,
    const float* __restrict__ bv, float* __restrict__ out) {
  int i = blockIdx.x * 256 + threadIdx.x;
  if (i >= LDQKV) return;
  float v;
  if (i < HDIM) v = bq[i];
  else if (i < 2 * HDIM) v = bk[i - HDIM];
  else v = bv[i - 2 * HDIM];
  out[i] = v;
}

// Phase-MERGED pipelined GEMM. C[m][n] = (A.W^T + bias) * (n<2048?scale:1)
// BMx256 tile, BK=32, ring-4 LDS slots. 8 waves (2M x 4N). Per K-tile ONE
// phase: {read all 12 (or 8) frags ; stage tile t+3 ; 32 (16) MFMA (setprio) ;
// counted vmcnt ; ONE barrier}. Rationale: the previous 2-phase/4-barrier
// structure serialized LDS-return and MFMA (T_iter fit sum of pipe minima);
// with one barrier/iter, iter t+1's ds_reads issue while iter t's matrix-pipe
// backlog drains. Race analysis: stage(t+3) overwrites slot (t-1)&3 whose
// reads returned before each wave's lgkmcnt->MFMA->barrier in iter t-1 (the
// end-of-iter barrier orders that against this stage). Counted vmcnt before
// the barrier guarantees tile t+1 landed before next iter's frag reads.
// LDS chunk swizzle: chunk ^= (row>>1)&3 (pre-swizzled global source, linear
// LDS dest). Requires M == 4096, K == 2048, Ndim % 256 == 0,
// grid = (4096/BM)*(Ndim/256).
template <int BM, bool OUT_F32>
__global__ void __launch_bounds__(512, 2) gemm3(
    const bf16* __restrict__ A, const bf16* __restrict__ W,
    const float* __restrict__ bias, void* __restrict__ Cout,
    int Ndim, float scale) {
  constexpr int NT = 64;            // K-tiles (2048/32)
  constexpr int FM = BM / 32;       // m-frags per wave (8 or 4)
  constexpr int ALD = BM / 128;     // A gloads/thread/tile (2 or 1)
  constexpr int LPT = ALD + 2;      // total gloads/thread/tile (4 or 3)
  constexpr int MPX = (4096 / BM) / 8;  // m-tiles per XCD (2 or 4)
  __shared__ bf16 As[4][BM * 32];
  __shared__ bf16 Bs[4][256 * 32];

  const int tid = threadIdx.x;
  const int l = tid & 63;
  const int w = tid >> 6;          // 0..7
  const int wm = w >> 2;           // 0..1
  const int wn = w & 3;            // 0..3

  // A-resident XCD mapping: xcd = wid&7 owns MPX m-tiles, sweeps all n
  const int wid = blockIdx.x;
  const int j = wid >> 3;
  const int m0 = ((wid & 7) * MPX + (j & (MPX - 1))) * BM;
  const int n0 = (j / MPX) * 256;

  const float secsc = (n0 < 2048) ? scale : 1.0f;

  // staging: thread t loads chunk (i*512 + t); chunk L -> row L>>2, inchunk
  // L&3; LDS dest linear; SOURCE col chunk = (t&3) ^ ((row>>1)&3), row>>1 bits
  // from (t>>3)&3 (i*128 rows keep alignment)
  const int rowA = tid >> 2;                                 // 0..127
  const int cg = (((tid & 3) ^ ((tid >> 3) & 3))) * 8;       // src col (bf16)

  auto stageA = [&](int s, int kt) {
    const int k0 = kt * 32 + cg;
#pragma unroll
    for (int i = 0; i < ALD; ++i)
      gload_lds16(A + (size_t)(m0 + i * 128 + rowA) * 2048 + k0,
                  &As[s][(i * 512 + w * 64) * 8]);
  };
  auto stageB = [&](int s, int kt) {
    const int k0 = kt * 32 + cg;
#pragma unroll
    for (int i = 0; i < 2; ++i)
      gload_lds16(W + (size_t)(n0 + i * 128 + rowA) * 2048 + k0,
                  &Bs[s][(i * 512 + w * 64) * 8]);
  };

  f32x4 acc[FM][4];
#pragma unroll
  for (int mf = 0; mf < FM; ++mf)
#pragma unroll
    for (int nf = 0; nf < 4; ++nf) acc[mf][nf] = {0.f, 0.f, 0.f, 0.f};

  // fragment reads: lane l wants src chunk l>>4 of row (base + (l&15));
  // stored at chunk (l>>4) ^ ((row>>1)&3); (row>>1)&3 == ((l&15)>>1)&3
  const int fr = l & 15;
  const int fch = (((l >> 4) ^ ((fr >> 1) & 3))) * 8;  // bf16 offset in row

  // prologue: stage tiles 0,1,2 -> slots 0,1,2 (3*LPT loads in flight)
  stageA(0, 0); stageB(0, 0);
  stageA(1, 1); stageB(1, 1);
  stageA(2, 2); stageB(2, 2);
  if constexpr (LPT == 4)
    asm volatile("s_waitcnt vmcnt(8)" ::: "memory");   // tile 0 landed
  else
    asm volatile("s_waitcnt vmcnt(6)" ::: "memory");
  __builtin_amdgcn_s_barrier();

  for (int t = 0; t < NT; ++t) {
    const int s = t & 3;
    const int sn = (t + 3) & 3;
    const bool st = (t + 3) < NT;

    // ---- single phase: all frag reads for this tile ----
    bf16x8 bf[4], af[FM];
#pragma unroll
    for (int nf = 0; nf < 4; ++nf)
      bf[nf] = *(const bf16x8*)&Bs[s][(wn * 64 + nf * 16 + fr) * 32 + fch];
#pragma unroll
    for (int f = 0; f < FM; ++f)
      af[f] = *(const bf16x8*)&As[s][(wm * (BM / 2) + f * 16 + fr) * 32 + fch];

    // prefetch tile t+3 into slot (t+3)&3 == (t-1)&3 (read-complete last iter)
    if (st) { stageA(sn, t + 3); stageB(sn, t + 3); }

    // all MFMAs for this K-tile (compiler inserts lgkmcnt before first use)
    __builtin_amdgcn_s_setprio(1);
#pragma unroll
    for (int f = 0; f < FM; ++f)
#pragma unroll
      for (int nf = 0; nf < 4; ++nf)
        acc[f][nf] = __builtin_amdgcn_mfma_f32_16x16x32_bf16(
            af[f], bf[nf], acc[f][nf], 0, 0, 0);
    __builtin_amdgcn_s_setprio(0);

    // counted vmcnt: tile t+1 must have landed before next iter's frag reads
    if (t < NT - 3) {
      if constexpr (LPT == 4)
        asm volatile("s_waitcnt vmcnt(8)" ::: "memory");
      else
        asm volatile("s_waitcnt vmcnt(6)" ::: "memory");
    } else if (t == NT - 3) {
      if constexpr (LPT == 4)
        asm volatile("s_waitcnt vmcnt(4)" ::: "memory");
      else
        asm volatile("s_waitcnt vmcnt(3)" ::: "memory");
    } else if (t == NT - 2) {
      asm volatile("s_waitcnt vmcnt(0)" ::: "memory");
    }
    if (t < NT - 1) __builtin_amdgcn_s_barrier();
  }

  // epilogue: C/D layout col=l&15, row=(l>>4)*4+j
  const int rj = (l >> 4) * 4;
#pragma unroll
  for (int mf = 0; mf < FM; ++mf)
#pragma unroll
    for (int nf = 0; nf < 4; ++nf) {
      const int col = n0 + wn * 64 + nf * 16 + fr;
      const float bvl = bias[col];
#pragma unroll
      for (int jj = 0; jj < 4; ++jj) {
        const int row = m0 + wm * (BM / 2) + mf * 16 + rj + jj;
        const float v = (acc[mf][nf][jj] + bvl) * secsc;
        if constexpr (OUT_F32)
          ((float*)Cout)[(size_t)row * Ndim + col] = v;
        else
          ((bf16*)Cout)[(size_t)row * Ndim + col] = (bf16)v;
      }
    }
}

// One-shot V transpose: QKV [b][s][4096 + h*64+d] -> Vt [b][h][d][s]
__global__ void __launch_bounds__(256) transpose_v(
    const bf16* __restrict__ QKV, bf16* __restrict__ Vt) {
  __shared__ bf16 T[64][72];
  const int t = threadIdx.x;
  const int s0 = blockIdx.x * 64;
  const int h = blockIdx.y, b = blockIdx.z;
  const size_t inb = (size_t)b * SEQLEN * LDQKV + 2 * HDIM + (size_t)h * HEADD;
#pragma unroll
  for (int i = 0; i < 2; ++i) {
    const int idx = t + i * 256;
    const int r = idx >> 3, c = (idx & 7) * 8;
    *(bf16x8*)&T[r][c] = *(const bf16x8*)&QKV[inb + (size_t)(s0 + r) * LDQKV + c];
  }
  __syncthreads();
  const size_t outb = (size_t)(b * NHEADS + h) * HEADD * SEQLEN + s0;
#pragma unroll
  for (int i = 0; i < 2; ++i) {
    const int idx = t + i * 256;
    const int d = idx >> 3, cs = (idx & 7) * 8;
    bf16x8 o;
#pragma unroll
    for (int j = 0; j < 8; ++j) o[j] = T[cs + j][d];
    *(bf16x8*)&Vt[outb + (size_t)d * SEQLEN + cs] = o;
  }
}

// Flash attention, causal, swapped-QK 32x32 MFMA, in-register softmax (base-2),
// 2-phase double-buffered staging with counted vmcnt + raw s_barrier,
// paired q-tiles for uniform work (each block: 36 k-tiles total).
// Q pre-scaled by 0.125*log2(e). Q,K in fused QKV [b][s][LDQKV]; Vt [b][h][d][s].
__global__ void __launch_bounds__(256) attn4(
    const bf16* __restrict__ QKV, const bf16* __restrict__ Vt,
    bf16* __restrict__ O) {
  __shared__ bf16 Kl[2][64 * 64];  // [buf][kk][d], 16B-chunk XOR-swizzled
  __shared__ bf16 Vl[2][64 * 64];  // [buf][d][kk], 16B-chunk XOR-swizzled

  const int tid = threadIdx.x;
  const int l = tid & 63;
  const int w = tid >> 6;
  const int lq = l & 31;
  const int g = l >> 5;
  const int h = blockIdx.y, b = blockIdx.z;
  const size_t baseQ = (size_t)b * SEQLEN * LDQKV + (size_t)h * HEADD;
  const size_t baseK = baseQ + HDIM;
  const size_t baseV = (size_t)(b * NHEADS + h) * HEADD * SEQLEN;
  const size_t baseO = (size_t)b * SEQLEN * HDIM + (size_t)h * HEADD;

  const int L0 = w * 128 + l;
  const int L1 = w * 128 + 64 + l;
  const int r0 = L0 >> 3, gc0 = ((L0 & 7) ^ (r0 & 7)) * 8;
  const int r1 = L1 >> 3, gc1 = ((L1 & 7) ^ (r1 & 7)) * 8;
  const int dst0 = (w * 128) * 8;
  const int dst1 = (w * 128 + 64) * 8;

  auto stage = [&](int bufi, int kt) {
    const int k0s = kt * 64;
    gload_lds16(QKV + baseK + (size_t)(k0s + r0) * LDQKV + gc0, &Kl[bufi][dst0]);
    gload_lds16(QKV + baseK + (size_t)(k0s + r1) * LDQKV + gc1, &Kl[bufi][dst1]);
    gload_lds16(Vt + baseV + (size_t)r0 * SEQLEN + k0s + gc0, &Vl[bufi][dst0]);
    gload_lds16(Vt + baseV + (size_t)r1 * SEQLEN + k0s + gc1, &Vl[bufi][dst1]);
  };

#pragma unroll
  for (int seg = 0; seg < 2; ++seg) {
    const int qt = seg ? blockIdx.x : (NQT - 1 - blockIdx.x);  // heavy first
    const int q0 = qt * 128;
    const int qw = q0 + w * 32;
    const int qa = qw + lq;

    bf16x8 qf[4];
#pragma unroll
    for (int ks = 0; ks < 4; ++ks)
      qf[ks] = *(const bf16x8*)&QKV[baseQ + (size_t)qa * LDQKV + ks * 16 + g * 8];

    f32x16 oacc0, oacc1;
#pragma unroll
    for (int r = 0; r < 16; ++r) { oacc0[r] = 0.f; oacc1[r] = 0.f; }
    float mrun = -__builtin_inff(), lrun = 0.f;

    const int nkt = q0 / 64 + 2;
    stage(0, 0);

    for (int kt = 0; kt < nkt; ++kt) {
      const int cur = kt & 1;
      const int k0 = kt * 64;
      if (kt + 1 < nkt) {
        stage(cur ^ 1, kt + 1);
        asm volatile("s_waitcnt vmcnt(4)" ::: "memory");
      } else {
        asm volatile("s_waitcnt vmcnt(0)" ::: "memory");
      }
      __builtin_amdgcn_s_barrier();

      if (k0 <= qw + 31) {
        f32x16 st0, st1;
#pragma unroll
        for (int r = 0; r < 16; ++r) { st0[r] = 0.f; st1[r] = 0.f; }
        __builtin_amdgcn_s_setprio(1);
#pragma unroll
        for (int ks = 0; ks < 4; ++ks) {
          const int cr = (((2 * ks + g) ^ (lq & 7))) * 8;
          bf16x8 kf0 = *(const bf16x8*)&Kl[cur][lq * 64 + cr];
          bf16x8 kf1 = *(const bf16x8*)&Kl[cur][(32 + lq) * 64 + cr];
          st0 = __builtin_amdgcn_mfma_f32_32x32x16_bf16(kf0, qf[ks], st0, 0, 0, 0);
          st1 = __builtin_amdgcn_mfma_f32_32x32x16_bf16(kf1, qf[ks], st1, 0, 0, 0);
        }
        __builtin_amdgcn_s_setprio(0);

        if (k0 + 63 > qw) {
#pragma unroll
          for (int r = 0; r < 16; ++r) {
            const int ro = (r & 3) + 8 * (r >> 2) + 4 * g;
            if (k0 + ro > qa) st0[r] = -__builtin_inff();
            if (k0 + 32 + ro > qa) st1[r] = -__builtin_inff();
          }
        }

        float mx[8];
#pragma unroll
        for (int r = 0; r < 8; ++r)
          mx[r] = fmaxf(max3f(st0[r], st0[r + 8], st1[r]), st1[r + 8]);
        const float ma = max3f(mx[0], mx[1], mx[2]);
        const float mb = max3f(mx[3], mx[4], mx[5]);
        const float mc = max3f(mx[6], mx[7], ma);
        const float mtree = fmaxf(mb, mc);
        const float pm = fmaxf(mtree, __shfl_xor(mtree, 32));

        const float mnew = fmaxf(mrun, pm);
        if (!__all(pm - mrun <= 11.0f)) {
          const float sc = __builtin_amdgcn_exp2f(mrun - mnew);
          lrun *= sc;
#pragma unroll
          for (int r = 0; r < 16; ++r) {
            const int ro = (r & 3) + 8 * (r >> 2) + 4 * g;
            const float scr = __shfl(sc, ro);
            oacc0[r] *= scr;
            oacc1[r] *= scr;
          }
          mrun = mnew;
        }

#pragma unroll
        for (int r = 0; r < 16; ++r) {
          st0[r] = __builtin_amdgcn_exp2f(st0[r] - mrun);
          st1[r] = __builtin_amdgcn_exp2f(st1[r] - mrun);
        }
        float sm[8];
#pragma unroll
        for (int r = 0; r < 8; ++r)
          sm[r] = (st0[r] + st0[r + 8]) + (st1[r] + st1[r + 8]);
#pragma unroll
        for (int s = 4; s > 0; s >>= 1)
#pragma unroll
          for (int r = 0; r < 4; ++r)
            if (r < s) sm[r] += sm[r + s];
        lrun += sm[0] + __shfl_xor(sm[0], 32);

        unsigned wd0[8], wd1[8];
#pragma unroll
        for (int i = 0; i < 8; ++i) {
          wd0[i] = cvtpk_bf16(st0[2 * i], st0[2 * i + 1]);
          wd1[i] = cvtpk_bf16(st1[2 * i], st1[2 * i + 1]);
        }
        bf16x8 paf[4];
#pragma unroll
        for (int kt2 = 0; kt2 < 2; ++kt2)
#pragma unroll
          for (int hf = 0; hf < 2; ++hf) {
            const unsigned* wsrc = kt2 ? wd1 : wd0;
            const unsigned a0 = wsrc[hf * 4 + 0], a1 = wsrc[hf * 4 + 1];
            const unsigned b0 = wsrc[hf * 4 + 2], b1 = wsrc[hf * 4 + 3];
            const unsigned sb0 = (unsigned)__shfl_xor((int)b0, 32);
            const unsigned sb1 = (unsigned)__shfl_xor((int)b1, 32);
            const unsigned sa0 = (unsigned)__shfl_xor((int)a0, 32);
            const unsigned sa1 = (unsigned)__shfl_xor((int)a1, 32);
            union { unsigned u[4]; bf16x8 v; } fu;
            fu.u[0] = g ? sb0 : a0;
            fu.u[1] = g ? sb1 : a1;
            fu.u[2] = g ? b0 : sa0;
            fu.u[3] = g ? b1 : sa1;
            paf[kt2 * 2 + hf] = fu.v;
          }

        __builtin_amdgcn_s_setprio(1);
#pragma unroll
        for (int s = 0; s < 4; ++s) {
          const int cr = (((2 * s + g) ^ (lq & 7))) * 8;
          bf16x8 vf0 = *(const bf16x8*)&Vl[cur][lq * 64 + cr];
          bf16x8 vf1 = *(const bf16x8*)&Vl[cur][(32 + lq) * 64 + cr];
          oacc0 = __builtin_amdgcn_mfma_f32_32x32x16_bf16(paf[s], vf0, oacc0, 0, 0, 0);
          oacc1 = __builtin_amdgcn_mfma_f32_32x32x16_bf16(paf[s], vf1, oacc1, 0, 0, 0);
        }
        __builtin_amdgcn_s_setprio(0);
      }
      __builtin_amdgcn_s_barrier();
    }

#pragma unroll
    for (int r = 0; r < 16; ++r) {
      const int ro = (r & 3) + 8 * (r >> 2) + 4 * g;
      const float lr = __shfl(lrun, ro);
      const float inv = 1.0f / lr;
      O[baseO + (size_t)(qw + ro) * HDIM + lq] = (bf16)(oacc0[r] * inv);
      O[baseO + (size_t)(qw + ro) * HDIM + 32 + lq] = (bf16)(oacc1[r] * inv);
    }
  }
}

extern "C" void kernel_launch(void* const* d_in, const int* in_sizes, int n_in,
                              void* d_out, int out_size, void* d_ws, size_t ws_size,
                              hipStream_t stream) {
  (void)in_sizes; (void)n_in; (void)out_size; (void)ws_size;
  const float* hs = (const float*)d_in[0];
  const float* wq = (const float*)d_in[1];
  const float* bq = (const float*)d_in[2];
  const float* wk = (const float*)d_in[3];
  const float* bk = (const float*)d_in[4];
  const float* wv = (const float*)d_in[5];
  const float* bv = (const float*)d_in[6];
  const float* wo = (const float*)d_in[7];
  const float* bo = (const float*)d_in[8];

  char* wsp = (char*)d_ws;
  bf16* hsb  = (bf16*)wsp; wsp += (size_t)MTOT * HDIM * sizeof(bf16);
  bf16* wqb  = (bf16*)wsp; wsp += (size_t)HDIM * HDIM * sizeof(bf16);
  bf16* wkb  = (bf16*)wsp; wsp += (size_t)HDIM * HDIM * sizeof(bf16);
  bf16* wvb  = (bf16*)wsp; wsp += (size_t)HDIM * HDIM * sizeof(bf16);
  bf16* wob  = (bf16*)wsp; wsp += (size_t)HDIM * HDIM * sizeof(bf16);
  bf16* QKVb = (bf16*)wsp; wsp += (size_t)MTOT * LDQKV * sizeof(bf16);
  float* biasqkv = (float*)wsp; wsp += (size_t)LDQKV * sizeof(float);
  bf16* aob = hsb;        // attn output aliases hsb (dead after QKV GEMM)
  bf16* Vtb = wqb;        // V^T aliases wqb+wkb (16MB, dead after QKV GEMM)

  const int nHS = MTOT * HDIM;
  const int nW = HDIM * HDIM;
  cvt_f32_to_bf16<<<nHS / 2048, 256, 0, stream>>>(hs, hsb, nHS);
  dim3 gc(nW / 2048, 4);
  cvt4_f32_to_bf16<<<gc, 256, 0, stream>>>(wq, wk, wv, wo, wqb, wkb, wvb, wob);
  pack_bias<<<LDQKV / 256, 256, 0, stream>>>(bq, bk, bv, biasqkv);

  // fused QKV GEMM: W = [wq|wk|wv], N=6144. BM=256 -> grid 16*24=384.
  // fold 1/sqrt(HD) * log2(e) into Q section for base-2 online softmax.
  gemm3<256, false><<<dim3(16 * (LDQKV / 256)), 512, 0, stream>>>(
      hsb, wqb, biasqkv, QKVb, LDQKV, 0.125f * 1.44269504f);

  dim3 gt(SEQLEN / 64, NHEADS, NBATCH);
  transpose_v<<<gt, 256, 0, stream>>>(QKVb, Vtb);

  dim3 ga(NQT / 2, NHEADS, NBATCH);
  attn4<<<ga, 256, 0, stream>>>(QKVb, Vtb, aob);

  // output projection: BM=128 -> grid 32*8=256 = exactly 1 full round
  gemm3<128, true><<<dim3(32 * (HDIM / 256)), 512, 0, stream>>>(
      aob, wob, bo, (float*)d_out, HDIM, 1.0f);
}

// Round 2
// 260.764 us; speedup vs baseline: 1.0574x; 1.0074x over previous
//
#include <hip/hip_runtime.h>
#include <hip/hip_bf16.h>

#define HDIM 2048
#define NHEADS 32
#define HEADD 64
#define NBATCH 2
#define SEQLEN 2048
#define MTOT (NBATCH * SEQLEN)
#define NQT (SEQLEN / 128)   // 16 q-tiles of 128 rows
#define LDQKV 6144           // fused QKV row stride

typedef __bf16 bf16;
typedef __bf16 bf16x8 __attribute__((ext_vector_type(8)));
typedef float f32x4 __attribute__((ext_vector_type(4)));
typedef float f32x8 __attribute__((ext_vector_type(8)));
typedef float f32x16 __attribute__((ext_vector_type(16)));

// global -> LDS async copy, 16B per lane; LDS dest is wave-uniform base + lane*16
__device__ __forceinline__ void gload_lds16(const bf16* g, bf16* l) {
  __builtin_amdgcn_global_load_lds(
      (const __attribute__((address_space(1))) void*)g,
      (__attribute__((address_space(3))) void*)l, 16, 0, 0);
}

__device__ __forceinline__ unsigned cvtpk_bf16(float lo, float hi) {
  unsigned r;
  asm("v_cvt_pk_bf16_f32 %0, %1, %2" : "=v"(r) : "v"(lo), "v"(hi));
  return r;
}

__device__ __forceinline__ float max3f(float a, float b, float c) {
  float r;
  asm("v_max3_f32 %0, %1, %2, %3" : "=v"(r) : "v"(a), "v"(b), "v"(c));
  return r;
}

__global__ void __launch_bounds__(256) cvt_f32_to_bf16(
    const float* __restrict__ src, bf16* __restrict__ dst, int n) {
  int i = (blockIdx.x * 256 + threadIdx.x) * 8;
  if (i >= n) return;
  f32x8 a = *(const f32x8*)(src + i);
  bf16x8 o;
#pragma unroll
  for (int j = 0; j < 8; ++j) o[j] = (bf16)a[j];
  *(bf16x8*)(dst + i) = o;
}

// 4 weight matrices in one dispatch (blockIdx.y selects)
__global__ void __launch_bounds__(256) cvt4_f32_to_bf16(
    const float* __restrict__ s0, const float* __restrict__ s1,
    const float* __restrict__ s2, const float* __restrict__ s3,
    bf16* __restrict__ d0, bf16* __restrict__ d1,
    bf16* __restrict__ d2, bf16* __restrict__ d3) {
  const float* src; bf16* dst;
  switch (blockIdx.y) {
    case 0: src = s0; dst = d0; break;
    case 1: src = s1; dst = d1; break;
    case 2: src = s2; dst = d2; break;
    default: src = s3; dst = d3; break;
  }
  int i = (blockIdx.x * 256 + threadIdx.x) * 8;
  f32x8 a = *(const f32x8*)(src + i);
  bf16x8 o;
#pragma unroll
  for (int j = 0; j < 8; ++j) o[j] = (bf16)a[j];
  *(bf16x8*)(dst + i) = o;
}

// pack bq|bk|bv -> biasqkv[6144]
__global__ void __launch_bounds__(256) pack_bias(
    const float* __restrict__ bq, const float* __restrict__ bk,
    const float* __restrict__ bv, float* __restrict__ out) {
  int i = blockIdx.x * 256 + threadIdx.x;
  if (i >= LDQKV) return;
  float v;
  if (i < HDIM) v = bq[i];
  else if (i < 2 * HDIM) v = bk[i - HDIM];
  else v = bv[i - 2 * HDIM];
  out[i] = v;
}

// ---------------------------------------------------------------------------
// m201-style 8-phase GEMM, 256x256 tile, BK=64, 2 LDS slots of 1 K-tile.
// C[m][n] = (A.W^T + bias) * (n<2048?scale:1).
// 8 waves (2M x 4N). Wave output 128x64 decomposed into 4 quadrants:
// rows q_m*128 + wm*64 + mf*16 (mf 0..3), cols q_n*128 + wn*32 + nf*16
// (nf 0..1) -- per-phase operand halves are BLOCK-UNIFORM, so staging can be
// half-tile-granular. Per K-tile, 4 phases (zigzag (0,0)->(0,1)->(1,1)->(1,0)):
//   j0: read A0(8)+B0(4); stage (T+1,Ah1);  barrier; 16 MFMA; barrier
//   j1: read B1(4);       stage (T+2,Ah0);  barrier; 16 MFMA; barrier
//   j2: read A1(8);       stage (T+2,Bh0);  barrier; 16 MFMA; barrier
//   j3:                   stage (T+2,Bh1);  barrier; 16 MFMA; vmcnt; barrier
// Hazard ledger: each LDS half's reads are >=2 barriers (and lgkm-before-MFMA)
// ahead of its overwriting stage. vmcnt(6) once per K-tile leaves the 3 newest
// half-tiles in flight; guarantees tile T+1 fully landed before its j0 reads
// (prologue: 7 halves staged, vmcnt(6); tail: vmcnt(0) at t==NT-2).
// LDS rows are 64 bf16 = 8 chunks of 16B; chunk swizzle c ^= (row&7) via
// pre-swizzled global source (linear LDS dest) and swizzled frag reads.
// Requires M==4096, K==2048, Ndim%256==0, grid = 16*(Ndim/256).
// ---------------------------------------------------------------------------
template <bool OUT_F32>
__global__ void __launch_bounds__(512, 2) gemm8p(
    const bf16* __restrict__ A, const bf16* __restrict__ W,
    const float* __restrict__ bias, void* __restrict__ Cout,
    int Ndim, float scale) {
  constexpr int NT = 32;  // K-tiles (2048/64)
  __shared__ bf16 As[2][2][128 * 64];  // [slot][half][row*64+k]
  __shared__ bf16 Bs[2][2][128 * 64];

  const int tid = threadIdx.x;
  const int l = tid & 63;
  const int w = tid >> 6;   // 0..7
  const int wm = w >> 2;    // 0..1
  const int wn = w & 3;     // 0..3

  // A-resident XCD mapping: xcd = wid&7 owns 2 m-tiles, sweeps all n
  const int wid = blockIdx.x;
  const int j = wid >> 3;
  const int m0 = ((wid & 7) * 2 + (j & 1)) * 256;
  const int n0 = (j >> 1) * 256;
  const float secsc = (n0 < 2048) ? scale : 1.0f;

  // staging: lane handles linear 16B chunk L = i*512 + tid (i=0,1);
  // r = L>>3 = i*64 + (tid>>3), c = L&7; source col-chunk = c ^ (r&7)
  const int r_ = tid >> 3;                                  // 0..63
  const int cs = (((tid & 7) ^ ((tid >> 3) & 7))) * 8;      // src col (bf16)

  auto stgA = [&](int slot, int half, int kt) {
    const bf16* g = A + (size_t)(m0 + half * 128) * 2048 + kt * 64 + cs;
#pragma unroll
    for (int i = 0; i < 2; ++i)
      gload_lds16(g + (size_t)(i * 64 + r_) * 2048,
                  &As[slot][half][(i * 512 + w * 64) * 8]);
  };
  auto stgB = [&](int slot, int half, int kt) {
    const bf16* g = W + (size_t)(n0 + half * 128) * 2048 + kt * 64 + cs;
#pragma unroll
    for (int i = 0; i < 2; ++i)
      gload_lds16(g + (size_t)(i * 64 + r_) * 2048,
                  &Bs[slot][half][(i * 512 + w * 64) * 8]);
  };

  f32x4 acc[2][2][4][2];
#pragma unroll
  for (int qm = 0; qm < 2; ++qm)
#pragma unroll
    for (int qn = 0; qn < 2; ++qn)
#pragma unroll
      for (int mf = 0; mf < 4; ++mf)
#pragma unroll
        for (int nf = 0; nf < 2; ++nf) acc[qm][qn][mf][nf] = {0.f, 0.f, 0.f, 0.f};

  // fragment reads: lane l wants global chunk ks*4 + (l>>4) of row base+(l&15);
  // stored at chunk ^ (row&7), row&7 == fr&7
  const int fr = l & 15;
  const int ch0 = (((l >> 4)) ^ (fr & 7)) * 8;       // ks=0, bf16 offset
  const int ch1 = (((l >> 4) + 4) ^ (fr & 7)) * 8;   // ks=1

#define RD_A(DST, SLOT, HALF)                                                  \
  _Pragma("unroll") for (int mf = 0; mf < 4; ++mf) {                           \
    const int rb = (wm * 64 + mf * 16 + fr) * 64;                              \
    DST[mf][0] = *(const bf16x8*)&As[SLOT][HALF][rb + ch0];                    \
    DST[mf][1] = *(const bf16x8*)&As[SLOT][HALF][rb + ch1];                    \
  }
#define RD_B(DST, SLOT, HALF)                                                  \
  _Pragma("unroll") for (int nf = 0; nf < 2; ++nf) {                           \
    const int rb = (wn * 32 + nf * 16 + fr) * 64;                              \
    DST[nf][0] = *(const bf16x8*)&Bs[SLOT][HALF][rb + ch0];                    \
    DST[nf][1] = *(const bf16x8*)&Bs[SLOT][HALF][rb + ch1];                    \
  }
#define MFMA_Q(QM, QN, AR, BR)                                                 \
  __builtin_amdgcn_s_setprio(1);                                               \
  _Pragma("unroll") for (int mf = 0; mf < 4; ++mf)                             \
      _Pragma("unroll") for (int nf = 0; nf < 2; ++nf)                         \
          _Pragma("unroll") for (int ks = 0; ks < 2; ++ks)                     \
              acc[QM][QN][mf][nf] = __builtin_amdgcn_mfma_f32_16x16x32_bf16(   \
                  AR[mf][ks], BR[nf][ks], acc[QM][QN][mf][nf], 0, 0, 0);       \
  __builtin_amdgcn_s_setprio(0);

  // prologue: tile0 all 4 halves + tile1 {Ah0,Bh0,Bh1}; (1,Ah1) comes at t=0 j0
  stgA(0, 0, 0); stgB(0, 0, 0); stgB(0, 1, 0); stgA(0, 1, 0);
  stgA(1, 0, 1); stgB(1, 0, 1); stgB(1, 1, 1);
  asm volatile("s_waitcnt vmcnt(6)" ::: "memory");  // tile0 landed
  __builtin_amdgcn_s_barrier();

  for (int t = 0; t < NT; ++t) {
    const int s = t & 1;
    bf16x8 a0[4][2], a1[4][2], b0[2][2], b1[2][2];

    // ---- phase j0: quadrant (0,0) ----
    RD_A(a0, s, 0);
    RD_B(b0, s, 0);
    if (t + 1 < NT) stgA(s ^ 1, 1, t + 1);
    __builtin_amdgcn_s_barrier();
    MFMA_Q(0, 0, a0, b0);
    __builtin_amdgcn_s_barrier();

    // ---- phase j1: quadrant (0,1) ----
    RD_B(b1, s, 1);
    if (t + 2 < NT) stgA(s, 0, t + 2);
    __builtin_amdgcn_s_barrier();
    MFMA_Q(0, 1, a0, b1);
    __builtin_amdgcn_s_barrier();

    // ---- phase j2: quadrant (1,1) ----
    RD_A(a1, s, 1);
    if (t + 2 < NT) stgB(s, 0, t + 2);
    __builtin_amdgcn_s_barrier();
    MFMA_Q(1, 1, a1, b1);
    __builtin_amdgcn_s_barrier();

    // ---- phase j3: quadrant (1,0) ----
    if (t + 2 < NT) stgB(s, 1, t + 2);
    __builtin_amdgcn_s_barrier();
    MFMA_Q(1, 0, a1, b0);
    if (t < NT - 2)
      asm volatile("s_waitcnt vmcnt(6)" ::: "memory");
    else
      asm volatile("s_waitcnt vmcnt(0)" ::: "memory");
    __builtin_amdgcn_s_barrier();
  }
#undef RD_A
#undef RD_B
#undef MFMA_Q

  // epilogue: C/D layout col=l&15, row=(l>>4)*4+jj
  const int rj = (l >> 4) * 4;
#pragma unroll
  for (int qm = 0; qm < 2; ++qm)
#pragma unroll
    for (int qn = 0; qn < 2; ++qn)
#pragma unroll
      for (int mf = 0; mf < 4; ++mf)
#pragma unroll
        for (int nf = 0; nf < 2; ++nf) {
          const int col = n0 + qn * 128 + wn * 32 + nf * 16 + fr;
          const float bvl = bias[col];
#pragma unroll
          for (int jj = 0; jj < 4; ++jj) {
            const int row = m0 + qm * 128 + wm * 64 + mf * 16 + rj + jj;
            const float v = (acc[qm][qn][mf][nf][jj] + bvl) * secsc;
            if constexpr (OUT_F32)
              ((float*)Cout)[(size_t)row * Ndim + col] = v;
            else
              ((bf16*)Cout)[(size_t)row * Ndim + col] = (bf16)v;
          }
        }
}

// Phase-merged pipelined GEMM (R1 structure) -- kept for the BM=128 output
// projection. BMx256 tile, BK=32, ring-4 LDS slots, 1 barrier/iter.
template <int BM, bool OUT_F32>
__global__ void __launch_bounds__(512, 2) gemm3(
    const bf16* __restrict__ A, const bf16* __restrict__ W,
    const float* __restrict__ bias, void* __restrict__ Cout,
    int Ndim, float scale) {
  constexpr int NT = 64;            // K-tiles (2048/32)
  constexpr int FM = BM / 32;       // m-frags per wave (8 or 4)
  constexpr int ALD = BM / 128;     // A gloads/thread/tile (2 or 1)
  constexpr int LPT = ALD + 2;      // total gloads/thread/tile (4 or 3)
  constexpr int MPX = (4096 / BM) / 8;  // m-tiles per XCD (2 or 4)
  __shared__ bf16 As[4][BM * 32];
  __shared__ bf16 Bs[4][256 * 32];

  const int tid = threadIdx.x;
  const int l = tid & 63;
  const int w = tid >> 6;          // 0..7
  const int wm = w >> 2;           // 0..1
  const int wn = w & 3;            // 0..3

  const int wid = blockIdx.x;
  const int j = wid >> 3;
  const int m0 = ((wid & 7) * MPX + (j & (MPX - 1))) * BM;
  const int n0 = (j / MPX) * 256;

  const float secsc = (n0 < 2048) ? scale : 1.0f;

  const int rowA = tid >> 2;                                 // 0..127
  const int cg = (((tid & 3) ^ ((tid >> 3) & 3))) * 8;       // src col (bf16)

  auto stageA = [&](int s, int kt) {
    const int k0 = kt * 32 + cg;
#pragma unroll
    for (int i = 0; i < ALD; ++i)
      gload_lds16(A + (size_t)(m0 + i * 128 + rowA) * 2048 + k0,
                  &As[s][(i * 512 + w * 64) * 8]);
  };
  auto stageB = [&](int s, int kt) {
    const int k0 = kt * 32 + cg;
#pragma unroll
    for (int i = 0; i < 2; ++i)
      gload_lds16(W + (size_t)(n0 + i * 128 + rowA) * 2048 + k0,
                  &Bs[s][(i * 512 + w * 64) * 8]);
  };

  f32x4 acc[FM][4];
#pragma unroll
  for (int mf = 0; mf < FM; ++mf)
#pragma unroll
    for (int nf = 0; nf < 4; ++nf) acc[mf][nf] = {0.f, 0.f, 0.f, 0.f};

  const int fr = l & 15;
  const int fch = (((l >> 4) ^ ((fr >> 1) & 3))) * 8;  // bf16 offset in row

  stageA(0, 0); stageB(0, 0);
  stageA(1, 1); stageB(1, 1);
  stageA(2, 2); stageB(2, 2);
  if constexpr (LPT == 4)
    asm volatile("s_waitcnt vmcnt(8)" ::: "memory");
  else
    asm volatile("s_waitcnt vmcnt(6)" ::: "memory");
  __builtin_amdgcn_s_barrier();

  for (int t = 0; t < NT; ++t) {
    const int s = t & 3;
    const int sn = (t + 3) & 3;
    const bool st = (t + 3) < NT;

    bf16x8 bf[4], af[FM];
#pragma unroll
    for (int nf = 0; nf < 4; ++nf)
      bf[nf] = *(const bf16x8*)&Bs[s][(wn * 64 + nf * 16 + fr) * 32 + fch];
#pragma unroll
    for (int f = 0; f < FM; ++f)
      af[f] = *(const bf16x8*)&As[s][(wm * (BM / 2) + f * 16 + fr) * 32 + fch];

    if (st) { stageA(sn, t + 3); stageB(sn, t + 3); }

    __builtin_amdgcn_s_setprio(1);
#pragma unroll
    for (int f = 0; f < FM; ++f)
#pragma unroll
      for (int nf = 0; nf < 4; ++nf)
        acc[f][nf] = __builtin_amdgcn_mfma_f32_16x16x32_bf16(
            af[f], bf[nf], acc[f][nf], 0, 0, 0);
    __builtin_amdgcn_s_setprio(0);

    if (t < NT - 3) {
      if constexpr (LPT == 4)
        asm volatile("s_waitcnt vmcnt(8)" ::: "memory");
      else
        asm volatile("s_waitcnt vmcnt(6)" ::: "memory");
    } else if (t == NT - 3) {
      if constexpr (LPT == 4)
        asm volatile("s_waitcnt vmcnt(4)" ::: "memory");
      else
        asm volatile("s_waitcnt vmcnt(3)" ::: "memory");
    } else if (t == NT - 2) {
      asm volatile("s_waitcnt vmcnt(0)" ::: "memory");
    }
    if (t < NT - 1) __builtin_amdgcn_s_barrier();
  }

  const int rj = (l >> 4) * 4;
#pragma unroll
  for (int mf = 0; mf < FM; ++mf)
#pragma unroll
    for (int nf = 0; nf < 4; ++nf) {
      const int col = n0 + wn * 64 + nf * 16 + fr;
      const float bvl = bias[col];
#pragma unroll
      for (int jj = 0; jj < 4; ++jj) {
        const int row = m0 + wm * (BM / 2) + mf * 16 + rj + jj;
        const float v = (acc[mf][nf][jj] + bvl) * secsc;
        if constexpr (OUT_F32)
          ((float*)Cout)[(size_t)row * Ndim + col] = v;
        else
          ((bf16*)Cout)[(size_t)row * Ndim + col] = (bf16)v;
      }
    }
}

// One-shot V transpose: QKV [b][s][4096 + h*64+d] -> Vt [b][h][d][s]
__global__ void __launch_bounds__(256) transpose_v(
    const bf16* __restrict__ QKV, bf16* __restrict__ Vt) {
  __shared__ bf16 T[64][72];
  const int t = threadIdx.x;
  const int s0 = blockIdx.x * 64;
  const int h = blockIdx.y, b = blockIdx.z;
  const size_t inb = (size_t)b * SEQLEN * LDQKV + 2 * HDIM + (size_t)h * HEADD;
#pragma unroll
  for (int i = 0; i < 2; ++i) {
    const int idx = t + i * 256;
    const int r = idx >> 3, c = (idx & 7) * 8;
    *(bf16x8*)&T[r][c] = *(const bf16x8*)&QKV[inb + (size_t)(s0 + r) * LDQKV + c];
  }
  __syncthreads();
  const size_t outb = (size_t)(b * NHEADS + h) * HEADD * SEQLEN + s0;
#pragma unroll
  for (int i = 0; i < 2; ++i) {
    const int idx = t + i * 256;
    const int d = idx >> 3, cs = (idx & 7) * 8;
    bf16x8 o;
#pragma unroll
    for (int j = 0; j < 8; ++j) o[j] = T[cs + j][d];
    *(bf16x8*)&Vt[outb + (size_t)d * SEQLEN + cs] = o;
  }
}

// Flash attention, causal, swapped-QK 32x32 MFMA, in-register softmax (base-2),
// 2-phase double-buffered staging with counted vmcnt + raw s_barrier,
// paired q-tiles for uniform work (each block: 36 k-tiles total).
// Q pre-scaled by 0.125*log2(e). Q,K in fused QKV [b][s][LDQKV]; Vt [b][h][d][s].
__global__ void __launch_bounds__(256) attn4(
    const bf16* __restrict__ QKV, const bf16* __restrict__ Vt,
    bf16* __restrict__ O) {
  __shared__ bf16 Kl[2][64 * 64];  // [buf][kk][d], 16B-chunk XOR-swizzled
  __shared__ bf16 Vl[2][64 * 64];  // [buf][d][kk], 16B-chunk XOR-swizzled

  const int tid = threadIdx.x;
  const int l = tid & 63;
  const int w = tid >> 6;
  const int lq = l & 31;
  const int g = l >> 5;
  const int h = blockIdx.y, b = blockIdx.z;
  const size_t baseQ = (size_t)b * SEQLEN * LDQKV + (size_t)h * HEADD;
  const size_t baseK = baseQ + HDIM;
  const size_t baseV = (size_t)(b * NHEADS + h) * HEADD * SEQLEN;
  const size_t baseO = (size_t)b * SEQLEN * HDIM + (size_t)h * HEADD;

  const int L0 = w * 128 + l;
  const int L1 = w * 128 + 64 + l;
  const int r0 = L0 >> 3, gc0 = ((L0 & 7) ^ (r0 & 7)) * 8;
  const int r1 = L1 >> 3, gc1 = ((L1 & 7) ^ (r1 & 7)) * 8;
  const int dst0 = (w * 128) * 8;
  const int dst1 = (w * 128 + 64) * 8;

  auto stage = [&](int bufi, int kt) {
    const int k0s = kt * 64;
    gload_lds16(QKV + baseK + (size_t)(k0s + r0) * LDQKV + gc0, &Kl[bufi][dst0]);
    gload_lds16(QKV + baseK + (size_t)(k0s + r1) * LDQKV + gc1, &Kl[bufi][dst1]);
    gload_lds16(Vt + baseV + (size_t)r0 * SEQLEN + k0s + gc0, &Vl[bufi][dst0]);
    gload_lds16(Vt + baseV + (size_t)r1 * SEQLEN + k0s + gc1, &Vl[bufi][dst1]);
  };

#pragma unroll
  for (int seg = 0; seg < 2; ++seg) {
    const int qt = seg ? blockIdx.x : (NQT - 1 - blockIdx.x);  // heavy first
    const int q0 = qt * 128;
    const int qw = q0 + w * 32;
    const int qa = qw + lq;

    bf16x8 qf[4];
#pragma unroll
    for (int ks = 0; ks < 4; ++ks)
      qf[ks] = *(const bf16x8*)&QKV[baseQ + (size_t)qa * LDQKV + ks * 16 + g * 8];

    f32x16 oacc0, oacc1;
#pragma unroll
    for (int r = 0; r < 16; ++r) { oacc0[r] = 0.f; oacc1[r] = 0.f; }
    float mrun = -__builtin_inff(), lrun = 0.f;

    const int nkt = q0 / 64 + 2;
    stage(0, 0);

    for (int kt = 0; kt < nkt; ++kt) {
      const int cur = kt & 1;
      const int k0 = kt * 64;
      if (kt + 1 < nkt) {
        stage(cur ^ 1, kt + 1);
        asm volatile("s_waitcnt vmcnt(4)" ::: "memory");
      } else {
        asm volatile("s_waitcnt vmcnt(0)" ::: "memory");
      }
      __builtin_amdgcn_s_barrier();

      if (k0 <= qw + 31) {
        f32x16 st0, st1;
#pragma unroll
        for (int r = 0; r < 16; ++r) { st0[r] = 0.f; st1[r] = 0.f; }
        __builtin_amdgcn_s_setprio(1);
#pragma unroll
        for (int ks = 0; ks < 4; ++ks) {
          const int cr = (((2 * ks + g) ^ (lq & 7))) * 8;
          bf16x8 kf0 = *(const bf16x8*)&Kl[cur][lq * 64 + cr];
          bf16x8 kf1 = *(const bf16x8*)&Kl[cur][(32 + lq) * 64 + cr];
          st0 = __builtin_amdgcn_mfma_f32_32x32x16_bf16(kf0, qf[ks], st0, 0, 0, 0);
          st1 = __builtin_amdgcn_mfma_f32_32x32x16_bf16(kf1, qf[ks], st1, 0, 0, 0);
        }
        __builtin_amdgcn_s_setprio(0);

        if (k0 + 63 > qw) {
#pragma unroll
          for (int r = 0; r < 16; ++r) {
            const int ro = (r & 3) + 8 * (r >> 2) + 4 * g;
            if (k0 + ro > qa) st0[r] = -__builtin_inff();
            if (k0 + 32 + ro > qa) st1[r] = -__builtin_inff();
          }
        }

        float mx[8];
#pragma unroll
        for (int r = 0; r < 8; ++r)
          mx[r] = fmaxf(max3f(st0[r], st0[r + 8], st1[r]), st1[r + 8]);
        const float ma = max3f(mx[0], mx[1], mx[2]);
        const float mb = max3f(mx[3], mx[4], mx[5]);
        const float mc = max3f(mx[6], mx[7], ma);
        const float mtree = fmaxf(mb, mc);
        const float pm = fmaxf(mtree, __shfl_xor(mtree, 32));

        const float mnew = fmaxf(mrun, pm);
        if (!__all(pm - mrun <= 11.0f)) {
          const float sc = __builtin_amdgcn_exp2f(mrun - mnew);
          lrun *= sc;
#pragma unroll
          for (int r = 0; r < 16; ++r) {
            const int ro = (r & 3) + 8 * (r >> 2) + 4 * g;
            const float scr = __shfl(sc, ro);
            oacc0[r] *= scr;
            oacc1[r] *= scr;
          }
          mrun = mnew;
        }

#pragma unroll
        for (int r = 0; r < 16; ++r) {
          st0[r] = __builtin_amdgcn_exp2f(st0[r] - mrun);
          st1[r] = __builtin_amdgcn_exp2f(st1[r] - mrun);
        }
        float sm[8];
#pragma unroll
        for (int r = 0; r < 8; ++r)
          sm[r] = (st0[r] + st0[r + 8]) + (st1[r] + st1[r + 8]);
#pragma unroll
        for (int s = 4; s > 0; s >>= 1)
#pragma unroll
          for (int r = 0; r < 4; ++r)
            if (r < s) sm[r] += sm[r + s];
        lrun += sm[0] + __shfl_xor(sm[0], 32);

        unsigned wd0[8], wd1[8];
#pragma unroll
        for (int i = 0; i < 8; ++i) {
          wd0[i] = cvtpk_bf16(st0[2 * i], st0[2 * i + 1]);
          wd1[i] = cvtpk_bf16(st1[2 * i], st1[2 * i + 1]);
        }
        bf16x8 paf[4];
#pragma unroll
        for (int kt2 = 0; kt2 < 2; ++kt2)
#pragma unroll
          for (int hf = 0; hf < 2; ++hf) {
            const unsigned* wsrc = kt2 ? wd1 : wd0;
            const unsigned a0 = wsrc[hf * 4 + 0], a1 = wsrc[hf * 4 + 1];
            const unsigned b0 = wsrc[hf * 4 + 2], b1 = wsrc[hf * 4 + 3];
            const unsigned sb0 = (unsigned)__shfl_xor((int)b0, 32);
            const unsigned sb1 = (unsigned)__shfl_xor((int)b1, 32);
            const unsigned sa0 = (unsigned)__shfl_xor((int)a0, 32);
            const unsigned sa1 = (unsigned)__shfl_xor((int)a1, 32);
            union { unsigned u[4]; bf16x8 v; } fu;
            fu.u[0] = g ? sb0 : a0;
            fu.u[1] = g ? sb1 : a1;
            fu.u[2] = g ? b0 : sa0;
            fu.u[3] = g ? b1 : sa1;
            paf[kt2 * 2 + hf] = fu.v;
          }

        __builtin_amdgcn_s_setprio(1);
#pragma unroll
        for (int s = 0; s < 4; ++s) {
          const int cr = (((2 * s + g) ^ (lq & 7))) * 8;
          bf16x8 vf0 = *(const bf16x8*)&Vl[cur][lq * 64 + cr];
          bf16x8 vf1 = *(const bf16x8*)&Vl[cur][(32 + lq) * 64 + cr];
          oacc0 = __builtin_amdgcn_mfma_f32_32x32x16_bf16(paf[s], vf0, oacc0, 0, 0, 0);
          oacc1 = __builtin_amdgcn_mfma_f32_32x32x16_bf16(paf[s], vf1, oacc1, 0, 0, 0);
        }
        __builtin_amdgcn_s_setprio(0);
      }
      __builtin_amdgcn_s_barrier();
    }

#pragma unroll
    for (int r = 0; r < 16; ++r) {
      const int ro = (r & 3) + 8 * (r >> 2) + 4 * g;
      const float lr = __shfl(lrun, ro);
      const float inv = 1.0f / lr;
      O[baseO + (size_t)(qw + ro) * HDIM + lq] = (bf16)(oacc0[r] * inv);
      O[baseO + (size_t)(qw + ro) * HDIM + 32 + lq] = (bf16)(oacc1[r] * inv);
    }
  }
}

extern "C" void kernel_launch(void* const* d_in, const int* in_sizes, int n_in,
                              void* d_out, int out_size, void* d_ws, size_t ws_size,
                              hipStream_t stream) {
  (void)in_sizes; (void)n_in; (void)out_size; (void)ws_size;
  const float* hs = (const float*)d_in[0];
  const float* wq = (const float*)d_in[1];
  const float* bq = (const float*)d_in[2];
  const float* wk = (const float*)d_in[3];
  const float* bk = (const float*)d_in[4];
  const float* wv = (const float*)d_in[5];
  const float* bv = (const float*)d_in[6];
  const float* wo = (const float*)d_in[7];
  const float* bo = (const float*)d_in[8];

  char* wsp = (char*)d_ws;
  bf16* hsb  = (bf16*)wsp; wsp += (size_t)MTOT * HDIM * sizeof(bf16);
  bf16* wqb  = (bf16*)wsp; wsp += (size_t)HDIM * HDIM * sizeof(bf16);
  bf16* wkb  = (bf16*)wsp; wsp += (size_t)HDIM * HDIM * sizeof(bf16);
  bf16* wvb  = (bf16*)wsp; wsp += (size_t)HDIM * HDIM * sizeof(bf16);
  bf16* wob  = (bf16*)wsp; wsp += (size_t)HDIM * HDIM * sizeof(bf16);
  bf16* QKVb = (bf16*)wsp; wsp += (size_t)MTOT * LDQKV * sizeof(bf16);
  float* biasqkv = (float*)wsp; wsp += (size_t)LDQKV * sizeof(float);
  bf16* aob = hsb;        // attn output aliases hsb (dead after QKV GEMM)
  bf16* Vtb = wqb;        // V^T aliases wqb+wkb (16MB, dead after QKV GEMM)

  const int nHS = MTOT * HDIM;
  const int nW = HDIM * HDIM;
  cvt_f32_to_bf16<<<nHS / 2048, 256, 0, stream>>>(hs, hsb, nHS);
  dim3 gc(nW / 2048, 4);
  cvt4_f32_to_bf16<<<gc, 256, 0, stream>>>(wq, wk, wv, wo, wqb, wkb, wvb, wob);
  pack_bias<<<LDQKV / 256, 256, 0, stream>>>(bq, bk, bv, biasqkv);

  // fused QKV GEMM: W = [wq|wk|wv], N=6144. 8-phase 256x256 -> grid 16*24=384.
  // fold 1/sqrt(HD) * log2(e) into Q section for base-2 online softmax.
  gemm8p<false><<<dim3(16 * (LDQKV / 256)), 512, 0, stream>>>(
      hsb, wqb, biasqkv, QKVb, LDQKV, 0.125f * 1.44269504f);

  dim3 gt(SEQLEN / 64, NHEADS, NBATCH);
  transpose_v<<<gt, 256, 0, stream>>>(QKVb, Vtb);

  dim3 ga(NQT / 2, NHEADS, NBATCH);
  attn4<<<ga, 256, 0, stream>>>(QKVb, Vtb, aob);

  // output projection: BM=128 -> grid 32*8=256 = exactly 1 full round
  gemm3<128, true><<<dim3(32 * (HDIM / 256)), 512, 0, stream>>>(
      aob, wob, bo, (float*)d_out, HDIM, 1.0f);
}

// Round 3
// 245.113 us; speedup vs baseline: 1.1250x; 1.0639x over previous
//
#include <hip/hip_runtime.h>
#include <hip/hip_bf16.h>

#define HDIM 2048
#define NHEADS 32
#define HEADD 64
#define NBATCH 2
#define SEQLEN 2048
#define MTOT (NBATCH * SEQLEN)
#define NQT (SEQLEN / 128)   // 16 q-tiles of 128 rows
#define LDQKV 6144           // fused QKV row stride

typedef __bf16 bf16;
typedef __bf16 bf16x8 __attribute__((ext_vector_type(8)));
typedef float f32x4 __attribute__((ext_vector_type(4)));
typedef float f32x8 __attribute__((ext_vector_type(8)));
typedef float f32x16 __attribute__((ext_vector_type(16)));

// global -> LDS async copy, 16B per lane; LDS dest is wave-uniform base + lane*16
__device__ __forceinline__ void gload_lds16(const bf16* g, bf16* l) {
  __builtin_amdgcn_global_load_lds(
      (const __attribute__((address_space(1))) void*)g,
      (__attribute__((address_space(3))) void*)l, 16, 0, 0);
}

__device__ __forceinline__ unsigned cvtpk_bf16(float lo, float hi) {
  unsigned r;
  asm("v_cvt_pk_bf16_f32 %0, %1, %2" : "=v"(r) : "v"(lo), "v"(hi));
  return r;
}

__device__ __forceinline__ float max3f(float a, float b, float c) {
  float r;
  asm("v_max3_f32 %0, %1, %2, %3" : "=v"(r) : "v"(a), "v"(b), "v"(c));
  return r;
}

__global__ void __launch_bounds__(256) cvt_f32_to_bf16(
    const float* __restrict__ src, bf16* __restrict__ dst, int n) {
  int i = (blockIdx.x * 256 + threadIdx.x) * 8;
  if (i >= n) return;
  f32x8 a = *(const f32x8*)(src + i);
  bf16x8 o;
#pragma unroll
  for (int j = 0; j < 8; ++j) o[j] = (bf16)a[j];
  *(bf16x8*)(dst + i) = o;
}

// 4 weight matrices in one dispatch (blockIdx.y selects)
__global__ void __launch_bounds__(256) cvt4_f32_to_bf16(
    const float* __restrict__ s0, const float* __restrict__ s1,
    const float* __restrict__ s2, const float* __restrict__ s3,
    bf16* __restrict__ d0, bf16* __restrict__ d1,
    bf16* __restrict__ d2, bf16* __restrict__ d3) {
  const float* src; bf16* dst;
  switch (blockIdx.y) {
    case 0: src = s0; dst = d0; break;
    case 1: src = s1; dst = d1; break;
    case 2: src = s2; dst = d2; break;
    default: src = s3; dst = d3; break;
  }
  int i = (blockIdx.x * 256 + threadIdx.x) * 8;
  f32x8 a = *(const f32x8*)(src + i);
  bf16x8 o;
#pragma unroll
  for (int j = 0; j < 8; ++j) o[j] = (bf16)a[j];
  *(bf16x8*)(dst + i) = o;
}

// pack bq|bk|bv -> biasqkv[6144]
__global__ void __launch_bounds__(256) pack_bias(
    const float* __restrict__ bq, const float* __restrict__ bk,
    const float* __restrict__ bv, float* __restrict__ out) {
  int i = blockIdx.x * 256 + threadIdx.x;
  if (i >= LDQKV) return;
  float v;
  if (i < HDIM) v = bq[i];
  else if (i < 2 * HDIM) v = bk[i - HDIM];
  else v = bv[i - 2 * HDIM];
  out[i] = v;
}

// ---------------------------------------------------------------------------
// QKV GEMM, exact-grid 2-blocks/CU variant. C[m][n] = (A.W^T + b) * colScale.
// 256x192 tile, 256 threads (4 waves, 2M x 2N; wave output 128x96 = 8mf x 6nf),
// BK=32. Grid = (4096/256)*(6144/192) = 16*32 = 512 blocks = 256 CUs x 2
// blocks exactly -> one round, zero tail. Two INDEPENDENT blocks per CU give
// read-window/MFMA-window overlap at the CU level (barriers sync only 4 waves).
// LDS: A ring-2 (2x16KB) + B ring-3 (3x12KB) = 68 KB -> 2 blocks/CU (136<160).
// Per iter (ONE barrier): [read bf(6)+af(0..3); stage A(t+1) then B(t+2)
// (FIFO order matters); MFMA half0; read af(4..7) reusing regs; MFMA half1;
// vmcnt(3); barrier]. vmcnt(3) retires exactly A(t+1)+B(t+1), keeps B(t+2)
// in flight (counted, never drains). Hazard ledger: stage at t overwrites
// regions last read at t-1; vmcnt BEFORE barrier => at barrier_{t-1} all
// waves' frag reads of t-1 are complete (lgkm deps precede MFMA issue) and
// all waves' stages for tile t landed => deterministic WAR+RAW safety.
// Registers: acc 8x6 f32x4 = 192 (intrinsic: 25.2M outputs / 2048 waves);
// A-operand regs reused between halves to stay under 256/wave (2 waves/SIMD).
// LDS chunk-content swizzle c ^= (row>>1)&3 (rows = 64B = 4 chunks), same as
// proven gemm3; pre-swizzled global source, linear LDS dest, swizzled reads.
// ---------------------------------------------------------------------------
template <bool OUT_F32>
__global__ void __launch_bounds__(256, 2) gemmq(
    const bf16* __restrict__ A, const bf16* __restrict__ W,
    const float* __restrict__ bias, void* __restrict__ Cout,
    int Ndim, float scale) {
  constexpr int NT = 64;  // K-tiles (2048/32)
  __shared__ bf16 As[2][256 * 32];
  __shared__ bf16 Bs[3][192 * 32];

  const int tid = threadIdx.x;
  const int l = tid & 63;
  const int w = tid >> 6;   // 0..3
  const int wm = w >> 1;    // 0..1
  const int wn = w & 1;     // 0..1

  // A-resident XCD mapping: xcd = wid&7 owns 2 m-tiles; j&1 alternates m so
  // consecutive j reuse the same W n-tile in L2.
  const int wid = blockIdx.x;
  const int j = wid >> 3;                       // 0..63
  const int m0 = ((wid & 7) * 2 + (j & 1)) * 256;
  const int n0 = (j >> 1) * 192;

  // staging: thread handles 16B chunk L = i*256 + tid; row = L>>2 (64B rows),
  // in-row chunk = L&3; source col-chunk = (L&3) ^ ((row>>1)&3).
  // (row>>1)&3 == (tid>>3)&3 for all i (i*64 rows keep the 4-alignment).
  const int rowA = tid >> 2;                              // 0..63 (+ i*64)
  const int cg = (((tid & 3) ^ ((tid >> 3) & 3))) * 8;    // src col (bf16)

  auto stgA = [&](int s, int kt) {
    const bf16* g = A + (size_t)m0 * 2048 + kt * 32 + cg;
#pragma unroll
    for (int i = 0; i < 4; ++i)
      gload_lds16(g + (size_t)(i * 64 + rowA) * 2048,
                  &As[s][(i * 256 + w * 64) * 8]);
  };
  auto stgB = [&](int s, int kt) {
    const bf16* g = W + (size_t)n0 * 2048 + kt * 32 + cg;
#pragma unroll
    for (int i = 0; i < 3; ++i)
      gload_lds16(g + (size_t)(i * 64 + rowA) * 2048,
                  &Bs[s][(i * 256 + w * 64) * 8]);
  };

  f32x4 acc[8][6];
#pragma unroll
  for (int mf = 0; mf < 8; ++mf)
#pragma unroll
    for (int nf = 0; nf < 6; ++nf) acc[mf][nf] = {0.f, 0.f, 0.f, 0.f};

  // fragment reads: lane l wants source chunk l>>4 of row base+(l&15);
  // stored chunk = (l>>4) ^ ((row>>1)&3); (row>>1)&3 == ((fr>>1)&3)
  const int fr = l & 15;
  const int fch = (((l >> 4) ^ ((fr >> 1) & 3))) * 8;  // bf16 offset in row
  const int abase = (wm * 128 + fr) * 32 + fch;
  const int bbase = (wn * 96 + fr) * 32 + fch;

  // prologue: A(0), B(0), B(1); keep B(1) in flight
  stgA(0, 0);
  stgB(0, 0);
  stgB(1, 1);
  asm volatile("s_waitcnt vmcnt(3)" ::: "memory");
  __builtin_amdgcn_s_barrier();

  int sb = 0;  // t % 3
  for (int t = 0; t < NT; ++t) {
    const int sa = t & 1;
    int sb2 = sb + 2; if (sb2 >= 3) sb2 -= 3;  // (t+2) % 3

    bf16x8 bf[6], af[4];
#pragma unroll
    for (int nf = 0; nf < 6; ++nf)
      bf[nf] = *(const bf16x8*)&Bs[sb][bbase + nf * 16 * 32];
#pragma unroll
    for (int f = 0; f < 4; ++f)
      af[f] = *(const bf16x8*)&As[sa][abase + f * 16 * 32];

    // FIFO: A(t+1) issued BEFORE B(t+2) so vmcnt(3) retires A(t+1)+B(t+1)
    if (t + 1 < NT) stgA(sa ^ 1, t + 1);
    if (t + 2 < NT) stgB(sb2, t + 2);

    __builtin_amdgcn_s_setprio(1);
#pragma unroll
    for (int f = 0; f < 4; ++f)
#pragma unroll
      for (int nf = 0; nf < 6; ++nf)
        acc[f][nf] = __builtin_amdgcn_mfma_f32_16x16x32_bf16(
            af[f], bf[nf], acc[f][nf], 0, 0, 0);
    __builtin_amdgcn_s_setprio(0);

#pragma unroll
    for (int f = 0; f < 4; ++f)
      af[f] = *(const bf16x8*)&As[sa][abase + (4 + f) * 16 * 32];

    __builtin_amdgcn_s_setprio(1);
#pragma unroll
    for (int f = 0; f < 4; ++f)
#pragma unroll
      for (int nf = 0; nf < 6; ++nf)
        acc[4 + f][nf] = __builtin_amdgcn_mfma_f32_16x16x32_bf16(
            af[f], bf[nf], acc[4 + f][nf], 0, 0, 0);
    __builtin_amdgcn_s_setprio(0);

    if (t < NT - 2)
      asm volatile("s_waitcnt vmcnt(3)" ::: "memory");
    else
      asm volatile("s_waitcnt vmcnt(0)" ::: "memory");
    __builtin_amdgcn_s_barrier();

    sb = (sb == 2) ? 0 : sb + 1;
  }

  // epilogue: C/D layout col=l&15, row=(l>>4)*4+jj; per-column scale
  // (BN=192 tiles cross the n=2048 Q/K boundary)
  const int rj = (l >> 4) * 4;
#pragma unroll
  for (int mf = 0; mf < 8; ++mf)
#pragma unroll
    for (int nf = 0; nf < 6; ++nf) {
      const int col = n0 + wn * 96 + nf * 16 + fr;
      const float secsc = (col < 2048) ? scale : 1.0f;
      const float bvl = bias[col];
#pragma unroll
      for (int jj = 0; jj < 4; ++jj) {
        const int row = m0 + wm * 128 + mf * 16 + rj + jj;
        const float v = (acc[mf][nf][jj] + bvl) * secsc;
        if constexpr (OUT_F32)
          ((float*)Cout)[(size_t)row * Ndim + col] = v;
        else
          ((bf16*)Cout)[(size_t)row * Ndim + col] = (bf16)v;
      }
    }
}

// Phase-merged pipelined GEMM (R1 structure) -- kept for the BM=128 output
// projection (exact 256-block grid, 1 round). BMx256 tile, BK=32, ring-4 LDS
// slots, 1 barrier/iter.
template <int BM, bool OUT_F32>
__global__ void __launch_bounds__(512, 2) gemm3(
    const bf16* __restrict__ A, const bf16* __restrict__ W,
    const float* __restrict__ bias, void* __restrict__ Cout,
    int Ndim, float scale) {
  constexpr int NT = 64;            // K-tiles (2048/32)
  constexpr int FM = BM / 32;       // m-frags per wave (8 or 4)
  constexpr int ALD = BM / 128;     // A gloads/thread/tile (2 or 1)
  constexpr int LPT = ALD + 2;      // total gloads/thread/tile (4 or 3)
  constexpr int MPX = (4096 / BM) / 8;  // m-tiles per XCD (2 or 4)
  __shared__ bf16 As[4][BM * 32];
  __shared__ bf16 Bs[4][256 * 32];

  const int tid = threadIdx.x;
  const int l = tid & 63;
  const int w = tid >> 6;          // 0..7
  const int wm = w >> 2;           // 0..1
  const int wn = w & 3;            // 0..3

  const int wid = blockIdx.x;
  const int j = wid >> 3;
  const int m0 = ((wid & 7) * MPX + (j & (MPX - 1))) * BM;
  const int n0 = (j / MPX) * 256;

  const float secsc = (n0 < 2048) ? scale : 1.0f;

  const int rowA = tid >> 2;                                 // 0..127
  const int cg = (((tid & 3) ^ ((tid >> 3) & 3))) * 8;       // src col (bf16)

  auto stageA = [&](int s, int kt) {
    const int k0 = kt * 32 + cg;
#pragma unroll
    for (int i = 0; i < ALD; ++i)
      gload_lds16(A + (size_t)(m0 + i * 128 + rowA) * 2048 + k0,
                  &As[s][(i * 512 + w * 64) * 8]);
  };
  auto stageB = [&](int s, int kt) {
    const int k0 = kt * 32 + cg;
#pragma unroll
    for (int i = 0; i < 2; ++i)
      gload_lds16(W + (size_t)(n0 + i * 128 + rowA) * 2048 + k0,
                  &Bs[s][(i * 512 + w * 64) * 8]);
  };

  f32x4 acc[FM][4];
#pragma unroll
  for (int mf = 0; mf < FM; ++mf)
#pragma unroll
    for (int nf = 0; nf < 4; ++nf) acc[mf][nf] = {0.f, 0.f, 0.f, 0.f};

  const int fr = l & 15;
  const int fch = (((l >> 4) ^ ((fr >> 1) & 3))) * 8;  // bf16 offset in row

  stageA(0, 0); stageB(0, 0);
  stageA(1, 1); stageB(1, 1);
  stageA(2, 2); stageB(2, 2);
  if constexpr (LPT == 4)
    asm volatile("s_waitcnt vmcnt(8)" ::: "memory");
  else
    asm volatile("s_waitcnt vmcnt(6)" ::: "memory");
  __builtin_amdgcn_s_barrier();

  for (int t = 0; t < NT; ++t) {
    const int s = t & 3;
    const int sn = (t + 3) & 3;
    const bool st = (t + 3) < NT;

    bf16x8 bf[4], af[FM];
#pragma unroll
    for (int nf = 0; nf < 4; ++nf)
      bf[nf] = *(const bf16x8*)&Bs[s][(wn * 64 + nf * 16 + fr) * 32 + fch];
#pragma unroll
    for (int f = 0; f < FM; ++f)
      af[f] = *(const bf16x8*)&As[s][(wm * (BM / 2) + f * 16 + fr) * 32 + fch];

    if (st) { stageA(sn, t + 3); stageB(sn, t + 3); }

    __builtin_amdgcn_s_setprio(1);
#pragma unroll
    for (int f = 0; f < FM; ++f)
#pragma unroll
      for (int nf = 0; nf < 4; ++nf)
        acc[f][nf] = __builtin_amdgcn_mfma_f32_16x16x32_bf16(
            af[f], bf[nf], acc[f][nf], 0, 0, 0);
    __builtin_amdgcn_s_setprio(0);

    if (t < NT - 3) {
      if constexpr (LPT == 4)
        asm volatile("s_waitcnt vmcnt(8)" ::: "memory");
      else
        asm volatile("s_waitcnt vmcnt(6)" ::: "memory");
    } else if (t == NT - 3) {
      if constexpr (LPT == 4)
        asm volatile("s_waitcnt vmcnt(4)" ::: "memory");
      else
        asm volatile("s_waitcnt vmcnt(3)" ::: "memory");
    } else if (t == NT - 2) {
      asm volatile("s_waitcnt vmcnt(0)" ::: "memory");
    }
    if (t < NT - 1) __builtin_amdgcn_s_barrier();
  }

  const int rj = (l >> 4) * 4;
#pragma unroll
  for (int mf = 0; mf < FM; ++mf)
#pragma unroll
    for (int nf = 0; nf < 4; ++nf) {
      const int col = n0 + wn * 64 + nf * 16 + fr;
      const float bvl = bias[col];
#pragma unroll
      for (int jj = 0; jj < 4; ++jj) {
        const int row = m0 + wm * (BM / 2) + mf * 16 + rj + jj;
        const float v = (acc[mf][nf][jj] + bvl) * secsc;
        if constexpr (OUT_F32)
          ((float*)Cout)[(size_t)row * Ndim + col] = v;
        else
          ((bf16*)Cout)[(size_t)row * Ndim + col] = (bf16)v;
      }
    }
}

// One-shot V transpose: QKV [b][s][4096 + h*64+d] -> Vt [b][h][d][s]
__global__ void __launch_bounds__(256) transpose_v(
    const bf16* __restrict__ QKV, bf16* __restrict__ Vt) {
  __shared__ bf16 T[64][72];
  const int t = threadIdx.x;
  const int s0 = blockIdx.x * 64;
  const int h = blockIdx.y, b = blockIdx.z;
  const size_t inb = (size_t)b * SEQLEN * LDQKV + 2 * HDIM + (size_t)h * HEADD;
#pragma unroll
  for (int i = 0; i < 2; ++i) {
    const int idx = t + i * 256;
    const int r = idx >> 3, c = (idx & 7) * 8;
    *(bf16x8*)&T[r][c] = *(const bf16x8*)&QKV[inb + (size_t)(s0 + r) * LDQKV + c];
  }
  __syncthreads();
  const size_t outb = (size_t)(b * NHEADS + h) * HEADD * SEQLEN + s0;
#pragma unroll
  for (int i = 0; i < 2; ++i) {
    const int idx = t + i * 256;
    const int d = idx >> 3, cs = (idx & 7) * 8;
    bf16x8 o;
#pragma unroll
    for (int j = 0; j < 8; ++j) o[j] = T[cs + j][d];
    *(bf16x8*)&Vt[outb + (size_t)d * SEQLEN + cs] = o;
  }
}

// Flash attention, causal, swapped-QK 32x32 MFMA, in-register softmax (base-2),
// 2-phase double-buffered staging with counted vmcnt + raw s_barrier,
// paired q-tiles for uniform work (each block: 36 k-tiles total).
// Q pre-scaled by 0.125*log2(e). Q,K in fused QKV [b][s][LDQKV]; Vt [b][h][d][s].
__global__ void __launch_bounds__(256) attn4(
    const bf16* __restrict__ QKV, const bf16* __restrict__ Vt,
    bf16* __restrict__ O) {
  __shared__ bf16 Kl[2][64 * 64];  // [buf][kk][d], 16B-chunk XOR-swizzled
  __shared__ bf16 Vl[2][64 * 64];  // [buf][d][kk], 16B-chunk XOR-swizzled

  const int tid = threadIdx.x;
  const int l = tid & 63;
  const int w = tid >> 6;
  const int lq = l & 31;
  const int g = l >> 5;
  const int h = blockIdx.y, b = blockIdx.z;
  const size_t baseQ = (size_t)b * SEQLEN * LDQKV + (size_t)h * HEADD;
  const size_t baseK = baseQ + HDIM;
  const size_t baseV = (size_t)(b * NHEADS + h) * HEADD * SEQLEN;
  const size_t baseO = (size_t)b * SEQLEN * HDIM + (size_t)h * HEADD;

  const int L0 = w * 128 + l;
  const int L1 = w * 128 + 64 + l;
  const int r0 = L0 >> 3, gc0 = ((L0 & 7) ^ (r0 & 7)) * 8;
  const int r1 = L1 >> 3, gc1 = ((L1 & 7) ^ (r1 & 7)) * 8;
  const int dst0 = (w * 128) * 8;
  const int dst1 = (w * 128 + 64) * 8;

  auto stage = [&](int bufi, int kt) {
    const int k0s = kt * 64;
    gload_lds16(QKV + baseK + (size_t)(k0s + r0) * LDQKV + gc0, &Kl[bufi][dst0]);
    gload_lds16(QKV + baseK + (size_t)(k0s + r1) * LDQKV + gc1, &Kl[bufi][dst1]);
    gload_lds16(Vt + baseV + (size_t)r0 * SEQLEN + k0s + gc0, &Vl[bufi][dst0]);
    gload_lds16(Vt + baseV + (size_t)r1 * SEQLEN + k0s + gc1, &Vl[bufi][dst1]);
  };

#pragma unroll
  for (int seg = 0; seg < 2; ++seg) {
    const int qt = seg ? blockIdx.x : (NQT - 1 - blockIdx.x);  // heavy first
    const int q0 = qt * 128;
    const int qw = q0 + w * 32;
    const int qa = qw + lq;

    bf16x8 qf[4];
#pragma unroll
    for (int ks = 0; ks < 4; ++ks)
      qf[ks] = *(const bf16x8*)&QKV[baseQ + (size_t)qa * LDQKV + ks * 16 + g * 8];

    f32x16 oacc0, oacc1;
#pragma unroll
    for (int r = 0; r < 16; ++r) { oacc0[r] = 0.f; oacc1[r] = 0.f; }
    float mrun = -__builtin_inff(), lrun = 0.f;

    const int nkt = q0 / 64 + 2;
    stage(0, 0);

    for (int kt = 0; kt < nkt; ++kt) {
      const int cur = kt & 1;
      const int k0 = kt * 64;
      if (kt + 1 < nkt) {
        stage(cur ^ 1, kt + 1);
        asm volatile("s_waitcnt vmcnt(4)" ::: "memory");
      } else {
        asm volatile("s_waitcnt vmcnt(0)" ::: "memory");
      }
      __builtin_amdgcn_s_barrier();

      if (k0 <= qw + 31) {
        f32x16 st0, st1;
#pragma unroll
        for (int r = 0; r < 16; ++r) { st0[r] = 0.f; st1[r] = 0.f; }
        __builtin_amdgcn_s_setprio(1);
#pragma unroll
        for (int ks = 0; ks < 4; ++ks) {
          const int cr = (((2 * ks + g) ^ (lq & 7))) * 8;
          bf16x8 kf0 = *(const bf16x8*)&Kl[cur][lq * 64 + cr];
          bf16x8 kf1 = *(const bf16x8*)&Kl[cur][(32 + lq) * 64 + cr];
          st0 = __builtin_amdgcn_mfma_f32_32x32x16_bf16(kf0, qf[ks], st0, 0, 0, 0);
          st1 = __builtin_amdgcn_mfma_f32_32x32x16_bf16(kf1, qf[ks], st1, 0, 0, 0);
        }
        __builtin_amdgcn_s_setprio(0);

        if (k0 + 63 > qw) {
#pragma unroll
          for (int r = 0; r < 16; ++r) {
            const int ro = (r & 3) + 8 * (r >> 2) + 4 * g;
            if (k0 + ro > qa) st0[r] = -__builtin_inff();
            if (k0 + 32 + ro > qa) st1[r] = -__builtin_inff();
          }
        }

        float mx[8];
#pragma unroll
        for (int r = 0; r < 8; ++r)
          mx[r] = fmaxf(max3f(st0[r], st0[r + 8], st1[r]), st1[r + 8]);
        const float ma = max3f(mx[0], mx[1], mx[2]);
        const float mb = max3f(mx[3], mx[4], mx[5]);
        const float mc = max3f(mx[6], mx[7], ma);
        const float mtree = fmaxf(mb, mc);
        const float pm = fmaxf(mtree, __shfl_xor(mtree, 32));

        const float mnew = fmaxf(mrun, pm);
        if (!__all(pm - mrun <= 11.0f)) {
          const float sc = __builtin_amdgcn_exp2f(mrun - mnew);
          lrun *= sc;
#pragma unroll
          for (int r = 0; r < 16; ++r) {
            const int ro = (r & 3) + 8 * (r >> 2) + 4 * g;
            const float scr = __shfl(sc, ro);
            oacc0[r] *= scr;
            oacc1[r] *= scr;
          }
          mrun = mnew;
        }

#pragma unroll
        for (int r = 0; r < 16; ++r) {
          st0[r] = __builtin_amdgcn_exp2f(st0[r] - mrun);
          st1[r] = __builtin_amdgcn_exp2f(st1[r] - mrun);
        }
        float sm[8];
#pragma unroll
        for (int r = 0; r < 8; ++r)
          sm[r] = (st0[r] + st0[r + 8]) + (st1[r] + st1[r + 8]);
#pragma unroll
        for (int s = 4; s > 0; s >>= 1)
#pragma unroll
          for (int r = 0; r < 4; ++r)
            if (r < s) sm[r] += sm[r + s];
        lrun += sm[0] + __shfl_xor(sm[0], 32);

        unsigned wd0[8], wd1[8];
#pragma unroll
        for (int i = 0; i < 8; ++i) {
          wd0[i] = cvtpk_bf16(st0[2 * i], st0[2 * i + 1]);
          wd1[i] = cvtpk_bf16(st1[2 * i], st1[2 * i + 1]);
        }
        bf16x8 paf[4];
#pragma unroll
        for (int kt2 = 0; kt2 < 2; ++kt2)
#pragma unroll
          for (int hf = 0; hf < 2; ++hf) {
            const unsigned* wsrc = kt2 ? wd1 : wd0;
            const unsigned a0 = wsrc[hf * 4 + 0], a1 = wsrc[hf * 4 + 1];
            const unsigned b0 = wsrc[hf * 4 + 2], b1 = wsrc[hf * 4 + 3];
            const unsigned sb0 = (unsigned)__shfl_xor((int)b0, 32);
            const unsigned sb1 = (unsigned)__shfl_xor((int)b1, 32);
            const unsigned sa0 = (unsigned)__shfl_xor((int)a0, 32);
            const unsigned sa1 = (unsigned)__shfl_xor((int)a1, 32);
            union { unsigned u[4]; bf16x8 v; } fu;
            fu.u[0] = g ? sb0 : a0;
            fu.u[1] = g ? sb1 : a1;
            fu.u[2] = g ? b0 : sa0;
            fu.u[3] = g ? b1 : sa1;
            paf[kt2 * 2 + hf] = fu.v;
          }

        __builtin_amdgcn_s_setprio(1);
#pragma unroll
        for (int s = 0; s < 4; ++s) {
          const int cr = (((2 * s + g) ^ (lq & 7))) * 8;
          bf16x8 vf0 = *(const bf16x8*)&Vl[cur][lq * 64 + cr];
          bf16x8 vf1 = *(const bf16x8*)&Vl[cur][(32 + lq) * 64 + cr];
          oacc0 = __builtin_amdgcn_mfma_f32_32x32x16_bf16(paf[s], vf0, oacc0, 0, 0, 0);
          oacc1 = __builtin_amdgcn_mfma_f32_32x32x16_bf16(paf[s], vf1, oacc1, 0, 0, 0);
        }
        __builtin_amdgcn_s_setprio(0);
      }
      __builtin_amdgcn_s_barrier();
    }

#pragma unroll
    for (int r = 0; r < 16; ++r) {
      const int ro = (r & 3) + 8 * (r >> 2) + 4 * g;
      const float lr = __shfl(lrun, ro);
      const float inv = 1.0f / lr;
      O[baseO + (size_t)(qw + ro) * HDIM + lq] = (bf16)(oacc0[r] * inv);
      O[baseO + (size_t)(qw + ro) * HDIM + 32 + lq] = (bf16)(oacc1[r] * inv);
    }
  }
}

extern "C" void kernel_launch(void* const* d_in, const int* in_sizes, int n_in,
                              void* d_out, int out_size, void* d_ws, size_t ws_size,
                              hipStream_t stream) {
  (void)in_sizes; (void)n_in; (void)out_size; (void)ws_size;
  const float* hs = (const float*)d_in[0];
  const float* wq = (const float*)d_in[1];
  const float* bq = (const float*)d_in[2];
  const float* wk = (const float*)d_in[3];
  const float* bk = (const float*)d_in[4];
  const float* wv = (const float*)d_in[5];
  const float* bv = (const float*)d_in[6];
  const float* wo = (const float*)d_in[7];
  const float* bo = (const float*)d_in[8];

  char* wsp = (char*)d_ws;
  bf16* hsb  = (bf16*)wsp; wsp += (size_t)MTOT * HDIM * sizeof(bf16);
  bf16* wqb  = (bf16*)wsp; wsp += (size_t)HDIM * HDIM * sizeof(bf16);
  bf16* wkb  = (bf16*)wsp; wsp += (size_t)HDIM * HDIM * sizeof(bf16);
  bf16* wvb  = (bf16*)wsp; wsp += (size_t)HDIM * HDIM * sizeof(bf16);
  bf16* wob  = (bf16*)wsp; wsp += (size_t)HDIM * HDIM * sizeof(bf16);
  bf16* QKVb = (bf16*)wsp; wsp += (size_t)MTOT * LDQKV * sizeof(bf16);
  float* biasqkv = (float*)wsp; wsp += (size_t)LDQKV * sizeof(float);
  bf16* aob = hsb;        // attn output aliases hsb (dead after QKV GEMM)
  bf16* Vtb = wqb;        // V^T aliases wqb+wkb (16MB, dead after QKV GEMM)

  const int nHS = MTOT * HDIM;
  const int nW = HDIM * HDIM;
  cvt_f32_to_bf16<<<nHS / 2048, 256, 0, stream>>>(hs, hsb, nHS);
  dim3 gc(nW / 2048, 4);
  cvt4_f32_to_bf16<<<gc, 256, 0, stream>>>(wq, wk, wv, wo, wqb, wkb, wvb, wob);
  pack_bias<<<LDQKV / 256, 256, 0, stream>>>(bq, bk, bv, biasqkv);

  // fused QKV GEMM: W = [wq|wk|wv], N=6144. 256x192 tiles -> 16*32 = 512
  // blocks = 2 blocks/CU x 256 CUs, exactly one round.
  // fold 1/sqrt(HD) * log2(e) into Q section for base-2 online softmax.
  gemmq<false><<<dim3(512), 256, 0, stream>>>(
      hsb, wqb, biasqkv, QKVb, LDQKV, 0.125f * 1.44269504f);

  dim3 gt(SEQLEN / 64, NHEADS, NBATCH);
  transpose_v<<<gt, 256, 0, stream>>>(QKVb, Vtb);

  dim3 ga(NQT / 2, NHEADS, NBATCH);
  attn4<<<ga, 256, 0, stream>>>(QKVb, Vtb, aob);

  // output projection: BM=128 -> grid 32*8=256 = exactly 1 full round
  gemm3<128, true><<<dim3(32 * (HDIM / 256)), 512, 0, stream>>>(
      aob, wob, bo, (float*)d_out, HDIM, 1.0f);
}